// Round 1
// baseline (294.252 us; speedup 1.0000x reference)
//
#include <hip/hip_runtime.h>
#include <math.h>

#define B_ 32
#define C_ 3
#define H_ 512
#define W_ 512
#define NOUT 64
#define FAN (C_*H_*W_)          // 786432
#define CHUNKS 24
#define CHUNK_ELEMS (FAN / CHUNKS)  // 32768

// workspace layout (float offsets)
#define P_OFF 0                  // 32*5 accumulators
#define FX_OFF 256
#define FY_OFF (FX_OFF + B_*NOUT*W_)
// total ws: (256 + 2*1048576)*4 = ~8.4 MB

// ---------------- kernel 1: p[b,j] = sum_i X[b,i] * W_loc[i,j] ----------------
__global__ __launch_bounds__(256) void k_locnet(const float* __restrict__ X,
                                                const float* __restrict__ Wl,
                                                float* __restrict__ ws) {
    const int b = blockIdx.y;
    const int chunk = blockIdx.x;
    const int t = threadIdx.x;
    const float4* X4 = (const float4*)(X + (size_t)b * FAN + (size_t)chunk * CHUNK_ELEMS);

    float acc[5] = {0.f, 0.f, 0.f, 0.f, 0.f};
    const int nf4 = CHUNK_ELEMS / 4;  // 8192
    for (int k = t; k < nf4; k += 256) {
        float4 x = X4[k];
        float xv[4] = {x.x, x.y, x.z, x.w};
        size_t i0 = (size_t)chunk * CHUNK_ELEMS + (size_t)k * 4;
        const float4* W4 = (const float4*)(Wl + i0 * 5);  // i0 % 4 == 0 -> aligned
        float4 w0 = W4[0], w1 = W4[1], w2 = W4[2], w3 = W4[3], w4 = W4[4];
        float wv[20] = {w0.x, w0.y, w0.z, w0.w,
                        w1.x, w1.y, w1.z, w1.w,
                        w2.x, w2.y, w2.z, w2.w,
                        w3.x, w3.y, w3.z, w3.w,
                        w4.x, w4.y, w4.z, w4.w};
        #pragma unroll
        for (int e = 0; e < 4; e++) {
            #pragma unroll
            for (int j = 0; j < 5; j++) {
                acc[j] += xv[e] * wv[e * 5 + j];
            }
        }
    }

    // wave reduce (64 lanes)
    #pragma unroll
    for (int off = 32; off > 0; off >>= 1) {
        #pragma unroll
        for (int j = 0; j < 5; j++) acc[j] += __shfl_down(acc[j], off);
    }
    __shared__ float sred[4][5];
    const int wave = t >> 6, lane = t & 63;
    if (lane == 0) {
        #pragma unroll
        for (int j = 0; j < 5; j++) sred[wave][j] = acc[j];
    }
    __syncthreads();
    if (t < 5) {
        float s = sred[0][t] + sred[1][t] + sred[2][t] + sred[3][t];
        atomicAdd(&ws[P_OFF + b * 5 + t], s);
    }
}

// ---------------- kernel 2: build normalized Fx [b][n][W], Fy [b][n][H] ----------------
__global__ __launch_bounds__(256) void k_filters(const float* __restrict__ bl,
                                                 float* __restrict__ ws) {
    const int n = blockIdx.x;      // 0..63
    const int b = blockIdx.y;      // 0..31
    const int which = blockIdx.z;  // 0: Fx, 1: Fy
    const int t = threadIdx.x;

    const float p0 = ws[P_OFF + b * 5 + 0] + bl[0];
    const float p1 = ws[P_OFF + b * 5 + 1] + bl[1];
    const float p2 = ws[P_OFF + b * 5 + 2] + bl[2];
    const float p3 = ws[P_OFF + b * 5 + 3] + bl[3];

    const float g = (which == 0) ? 32.f * (p0 + 1.f) : 32.f * (p1 + 1.f);
    const float sigma2 = expf(p2);
    const float inv2s = 0.5f / sigma2;
    const float delta = expf(p3) * (511.0f / 63.0f);
    const float mean = g + delta * ((float)n - 32.5f);  // n - N/2 - 0.5

    float d0 = (float)t - mean;
    float f0 = expf(-d0 * d0 * inv2s);
    float d1 = (float)(t + 256) - mean;
    float f1 = expf(-d1 * d1 * inv2s);

    float s = f0 + f1;
    #pragma unroll
    for (int off = 32; off > 0; off >>= 1) s += __shfl_down(s, off);
    __shared__ float sred[4];
    __shared__ float stot;
    const int wave = t >> 6, lane = t & 63;
    if (lane == 0) sred[wave] = s;
    __syncthreads();
    if (t == 0) stot = sred[0] + sred[1] + sred[2] + sred[3] + 1e-4f;
    __syncthreads();
    const float scale = 1.0f / stot;

    float* dst = ws + (which == 0 ? FX_OFF : FY_OFF) + ((size_t)b * NOUT + n) * W_;
    dst[t] = f0 * scale;
    dst[t + 256] = f1 * scale;
}

// ---------------- kernel 3: out[b,c,n,m] += gamma * Fy_chunk @ (X_chunk @ Fx^T) ----------------
// grid: (8 h-chunks, 96 (b,c)); block 256 threads.
// GEMM1: G[h(64) x m(64)] = sum_w X[hbase+h][w] * Fx[m][w]
// GEMM2: partial[n(64) x m(64)] = sum_h Fy[n][hbase+h] * G[h][m]
__global__ __launch_bounds__(256) void k_glimpse(const float* __restrict__ X,
                                                 const float* __restrict__ bl,
                                                 const float* __restrict__ ws,
                                                 float* __restrict__ out) {
    const int hc = blockIdx.x;   // 0..7
    const int bc = blockIdx.y;   // 0..95  == b*3 + c
    const int b = bc / 3;
    const int t = threadIdx.x;
    const int th = t >> 4;       // 0..15
    const int tm = t & 15;       // 0..15
    const int h0 = th * 4;
    const int m0 = tm * 4;
    const int hbase = hc * 64;

    __shared__ float lds[3 * 64 * 65];
    float (*Xs)[65]  = (float (*)[65])(lds);             // [h][w] tile
    float (*Fxs)[65] = (float (*)[65])(lds + 64 * 65);   // [m][w] tile
    float (*Gs)[65]  = (float (*)[65])(lds + 2 * 64 * 65);
    float (*Fys)[65] = (float (*)[65])(lds);             // reuse Xs region: [h][n]

    const float* Xp  = X + (size_t)bc * H_ * W_;
    const float* Fxp = ws + FX_OFF + (size_t)b * NOUT * W_;
    const float* Fyp = ws + FY_OFF + (size_t)b * NOUT * W_;

    float g[4][4] = {};

    for (int wt = 0; wt < 8; wt++) {
        const int wbase = wt * 64;
        #pragma unroll
        for (int k = 0; k < 4; k++) {
            int idx = t + 256 * k;
            int row = idx >> 4;      // 0..63
            int wq = idx & 15;
            float4 xf = *(const float4*)(Xp + (size_t)(hbase + row) * W_ + wbase + wq * 4);
            Xs[row][wq * 4 + 0] = xf.x;
            Xs[row][wq * 4 + 1] = xf.y;
            Xs[row][wq * 4 + 2] = xf.z;
            Xs[row][wq * 4 + 3] = xf.w;
            float4 ff = *(const float4*)(Fxp + (size_t)row * W_ + wbase + wq * 4);
            Fxs[row][wq * 4 + 0] = ff.x;
            Fxs[row][wq * 4 + 1] = ff.y;
            Fxs[row][wq * 4 + 2] = ff.z;
            Fxs[row][wq * 4 + 3] = ff.w;
        }
        __syncthreads();
        #pragma unroll 4
        for (int w = 0; w < 64; w++) {
            float xv[4], fv[4];
            #pragma unroll
            for (int i = 0; i < 4; i++) xv[i] = Xs[h0 + i][w];
            #pragma unroll
            for (int j = 0; j < 4; j++) fv[j] = Fxs[m0 + j][w];
            #pragma unroll
            for (int i = 0; i < 4; i++)
                #pragma unroll
                for (int j = 0; j < 4; j++) g[i][j] += xv[i] * fv[j];
        }
        __syncthreads();  // before next staging overwrites Xs/Fxs
    }

    // G -> LDS
    #pragma unroll
    for (int i = 0; i < 4; i++)
        #pragma unroll
        for (int j = 0; j < 4; j++) Gs[h0 + i][m0 + j] = g[i][j];

    // stage Fy chunk transposed: Fys[h_local][n]
    #pragma unroll
    for (int k = 0; k < 4; k++) {
        int idx = t + 256 * k;
        int n = idx >> 4;        // 0..63
        int hq = idx & 15;
        float4 ff = *(const float4*)(Fyp + (size_t)n * W_ + hbase + hq * 4);
        Fys[hq * 4 + 0][n] = ff.x;
        Fys[hq * 4 + 1][n] = ff.y;
        Fys[hq * 4 + 2][n] = ff.z;
        Fys[hq * 4 + 3][n] = ff.w;
    }
    __syncthreads();

    // GEMM2
    float a2[4][4] = {};
    const int n0 = h0;
    #pragma unroll 4
    for (int hl = 0; hl < 64; hl++) {
        float fy[4], gv[4];
        #pragma unroll
        for (int i = 0; i < 4; i++) fy[i] = Fys[hl][n0 + i];
        #pragma unroll
        for (int j = 0; j < 4; j++) gv[j] = Gs[hl][m0 + j];
        #pragma unroll
        for (int i = 0; i < 4; i++)
            #pragma unroll
            for (int j = 0; j < 4; j++) a2[i][j] += fy[i] * gv[j];
    }

    const float gamma = expf(ws[P_OFF + b * 5 + 4] + bl[4]);
    float* outp = out + (size_t)bc * NOUT * NOUT;
    #pragma unroll
    for (int i = 0; i < 4; i++)
        #pragma unroll
        for (int j = 0; j < 4; j++)
            atomicAdd(&outp[(n0 + i) * NOUT + (m0 + j)], gamma * a2[i][j]);
}

extern "C" void kernel_launch(void* const* d_in, const int* in_sizes, int n_in,
                              void* d_out, int out_size, void* d_ws, size_t ws_size,
                              hipStream_t stream) {
    const float* X  = (const float*)d_in[0];
    const float* Wl = (const float*)d_in[1];
    const float* bl = (const float*)d_in[2];
    float* out = (float*)d_out;
    float* ws  = (float*)d_ws;

    // zero p accumulators and output (both poisoned before each call)
    hipMemsetAsync(ws, 0, 1024, stream);
    hipMemsetAsync(out, 0, (size_t)out_size * sizeof(float), stream);

    k_locnet<<<dim3(CHUNKS, B_), 256, 0, stream>>>(X, Wl, ws);
    k_filters<<<dim3(NOUT, B_, 2), 256, 0, stream>>>(bl, ws);
    k_glimpse<<<dim3(8, B_ * C_), 256, 0, stream>>>(X, bl, ws, out);
}

// Round 2
// 245.869 us; speedup vs baseline: 1.1968x; 1.1968x over previous
//
#include <hip/hip_runtime.h>
#include <math.h>

#define B_ 32
#define C_ 3
#define H_ 512
#define W_ 512
#define NOUT 64
#define FAN (C_*H_*W_)          // 786432

// locnet decomposition
#define CHUNKS 96
#define CELEMS (FAN / CHUNKS)   // 8192
#define BGROUPS 4               // 8 batches per block

// workspace layout (float offsets)
#define P_OFF 0                 // 32*5 accumulators (zeroed each call)
#define FX_OFF 256
#define FY_OFF (FX_OFF + B_*NOUT*W_)

// ---------------- kernel 1: p[b,j] = sum_i X[b,i] * W_loc[i,j] ----------------
// Each block: one chunk of k-range x 8 batches. W chunk loaded once per 8 batches.
__global__ __launch_bounds__(256) void k_locnet(const float* __restrict__ X,
                                                const float* __restrict__ Wl,
                                                float* __restrict__ ws) {
    const int chunk = blockIdx.x;      // 0..95
    const int b0 = blockIdx.y * 8;     // 0,8,16,24
    const int t = threadIdx.x;

    float acc[8][5] = {};
    const size_t base = (size_t)chunk * CELEMS;

    for (int k = t; k < CELEMS / 4; k += 256) {   // 8 iterations
        const size_t i0 = base + (size_t)k * 4;
        const float4* W4 = (const float4*)(Wl + i0 * 5);  // i0 % 4 == 0 -> 16B aligned
        float4 w0 = W4[0], w1 = W4[1], w2 = W4[2], w3 = W4[3], w4 = W4[4];
        float wv[20] = {w0.x, w0.y, w0.z, w0.w,
                        w1.x, w1.y, w1.z, w1.w,
                        w2.x, w2.y, w2.z, w2.w,
                        w3.x, w3.y, w3.z, w3.w,
                        w4.x, w4.y, w4.z, w4.w};
        #pragma unroll
        for (int bb = 0; bb < 8; bb++) {
            float4 x = *(const float4*)(X + (size_t)(b0 + bb) * FAN + i0);
            float xv[4] = {x.x, x.y, x.z, x.w};
            #pragma unroll
            for (int e = 0; e < 4; e++)
                #pragma unroll
                for (int j = 0; j < 5; j++)
                    acc[bb][j] += xv[e] * wv[e * 5 + j];
        }
    }

    // wave reduce (64 lanes) over all 40 accumulators
    #pragma unroll
    for (int off = 32; off > 0; off >>= 1)
        #pragma unroll
        for (int bb = 0; bb < 8; bb++)
            #pragma unroll
            for (int j = 0; j < 5; j++)
                acc[bb][j] += __shfl_down(acc[bb][j], off);

    __shared__ float sred[4][40];
    const int wave = t >> 6, lane = t & 63;
    if (lane == 0) {
        #pragma unroll
        for (int bb = 0; bb < 8; bb++)
            #pragma unroll
            for (int j = 0; j < 5; j++)
                sred[wave][bb * 5 + j] = acc[bb][j];
    }
    __syncthreads();
    if (t < 40) {
        float s = sred[0][t] + sred[1][t] + sred[2][t] + sred[3][t];
        atomicAdd(&ws[P_OFF + b0 * 5 + t], s);  // t = bb*5+j  ->  (b0+bb)*5+j
    }
}

// ---------------- kernel 2: build normalized Fx [b][n][W], Fy [b][n][H] ----------------
__global__ __launch_bounds__(256) void k_filters(const float* __restrict__ bl,
                                                 float* __restrict__ ws) {
    const int n = blockIdx.x;      // 0..63
    const int b = blockIdx.y;      // 0..31
    const int which = blockIdx.z;  // 0: Fx, 1: Fy
    const int t = threadIdx.x;

    const float p0 = ws[P_OFF + b * 5 + 0] + bl[0];
    const float p1 = ws[P_OFF + b * 5 + 1] + bl[1];
    const float p2 = ws[P_OFF + b * 5 + 2] + bl[2];
    const float p3 = ws[P_OFF + b * 5 + 3] + bl[3];

    const float g = (which == 0) ? 32.f * (p0 + 1.f) : 32.f * (p1 + 1.f);
    const float sigma2 = expf(p2);
    const float inv2s = 0.5f / sigma2;
    const float delta = expf(p3) * (511.0f / 63.0f);
    const float mean = g + delta * ((float)n - 32.5f);  // n - N/2 - 0.5

    float d0 = (float)t - mean;
    float f0 = expf(-d0 * d0 * inv2s);
    float d1 = (float)(t + 256) - mean;
    float f1 = expf(-d1 * d1 * inv2s);

    float s = f0 + f1;
    #pragma unroll
    for (int off = 32; off > 0; off >>= 1) s += __shfl_down(s, off);
    __shared__ float sred[4];
    __shared__ float stot;
    const int wave = t >> 6, lane = t & 63;
    if (lane == 0) sred[wave] = s;
    __syncthreads();
    if (t == 0) stot = sred[0] + sred[1] + sred[2] + sred[3] + 1e-4f;
    __syncthreads();
    const float scale = 1.0f / stot;

    float* dst = ws + (which == 0 ? FX_OFF : FY_OFF) + ((size_t)b * NOUT + n) * W_;
    dst[t] = f0 * scale;
    dst[t + 256] = f1 * scale;
}

// ---------------- kernel 3: out[b,c] += gamma * Fy_chunk @ (X_chunk @ Fx^T) ----------------
// grid: (8 h-chunks, 96 (b,c)); block 256.
// Microtile 4x4 interleaved: thread (th,tm) owns rows {th+16i}, cols {tm+16j}.
// LDS rows padded to 66 floats: 8B-aligned rows, and 16-lane stride of 66 floats
// covers all 32 banks exactly once -> conflict-free ds_read_b64.
__global__ __launch_bounds__(256) void k_glimpse(const float* __restrict__ X,
                                                 const float* __restrict__ bl,
                                                 const float* __restrict__ ws,
                                                 float* __restrict__ out) {
    const int hc = blockIdx.x;   // 0..7
    const int bc = blockIdx.y;   // 0..95  == b*3 + c
    const int b = bc / 3;
    const int t = threadIdx.x;
    const int th = t >> 4;       // 0..15
    const int tm = t & 15;       // 0..15
    const int hbase = hc * 64;

    __shared__ float lds[2 * 64 * 66];   // 33.8 KB -> 4 blocks/CU
    float (*Xs)[66]  = (float (*)[66])(lds);             // [h][w]
    float (*Fxs)[66] = (float (*)[66])(lds + 64 * 66);   // [m][w]
    // aliases, valid after GEMM1's final barrier:
    float (*GsT)[66] = (float (*)[66])(lds);             // [m][h]
    float (*Fys)[66] = (float (*)[66])(lds + 64 * 66);   // [n][h]

    const float* Xp  = X + (size_t)bc * (H_ * W_) + (size_t)hbase * W_;
    const float* Fxp = ws + FX_OFF + (size_t)b * NOUT * W_;
    const float* Fyp = ws + FY_OFF + (size_t)b * NOUT * W_;

    float g[4][4] = {};

    for (int wt = 0; wt < 8; wt++) {
        const int wbase = wt * 64;
        #pragma unroll
        for (int k = 0; k < 4; k++) {
            int idx = t + 256 * k;
            int row = idx >> 4;      // 0..63
            int wq = idx & 15;
            float4 xf = *(const float4*)(Xp + (size_t)row * W_ + wbase + wq * 4);
            float4 ff = *(const float4*)(Fxp + (size_t)row * W_ + wbase + wq * 4);
            float* xd = &Xs[row][wq * 4];
            xd[0] = xf.x; xd[1] = xf.y; xd[2] = xf.z; xd[3] = xf.w;
            float* fd = &Fxs[row][wq * 4];
            fd[0] = ff.x; fd[1] = ff.y; fd[2] = ff.z; fd[3] = ff.w;
        }
        __syncthreads();
        #pragma unroll 4
        for (int w = 0; w < 64; w += 2) {
            float2 xv[4], fv[4];
            #pragma unroll
            for (int i = 0; i < 4; i++) xv[i] = *(const float2*)&Xs[th + 16 * i][w];
            #pragma unroll
            for (int j = 0; j < 4; j++) fv[j] = *(const float2*)&Fxs[tm + 16 * j][w];
            #pragma unroll
            for (int i = 0; i < 4; i++)
                #pragma unroll
                for (int j = 0; j < 4; j++) {
                    g[i][j] += xv[i].x * fv[j].x;
                    g[i][j] += xv[i].y * fv[j].y;
                }
        }
        __syncthreads();
    }

    // G -> LDS transposed: GsT[m][h]
    #pragma unroll
    for (int i = 0; i < 4; i++)
        #pragma unroll
        for (int j = 0; j < 4; j++)
            GsT[tm + 16 * j][th + 16 * i] = g[i][j];

    // stage Fy chunk: Fys[n][h_local]
    #pragma unroll
    for (int k = 0; k < 4; k++) {
        int idx = t + 256 * k;
        int n = idx >> 4;        // 0..63
        int hq = idx & 15;
        float4 ff = *(const float4*)(Fyp + (size_t)n * W_ + hbase + hq * 4);
        float* fd = &Fys[n][hq * 4];
        fd[0] = ff.x; fd[1] = ff.y; fd[2] = ff.z; fd[3] = ff.w;
    }
    __syncthreads();

    // GEMM2: out[n][m] = sum_h Fy[n][h] * G[h][m]; both operands contiguous along h
    float a2[4][4] = {};
    #pragma unroll 4
    for (int hl = 0; hl < 64; hl += 2) {
        float2 fy[4], gv[4];
        #pragma unroll
        for (int i = 0; i < 4; i++) fy[i] = *(const float2*)&Fys[th + 16 * i][hl];
        #pragma unroll
        for (int j = 0; j < 4; j++) gv[j] = *(const float2*)&GsT[tm + 16 * j][hl];
        #pragma unroll
        for (int i = 0; i < 4; i++)
            #pragma unroll
            for (int j = 0; j < 4; j++) {
                a2[i][j] += fy[i].x * gv[j].x;
                a2[i][j] += fy[i].y * gv[j].y;
            }
    }

    const float gamma = expf(ws[P_OFF + b * 5 + 4] + bl[4]);
    float* outp = out + (size_t)bc * (NOUT * NOUT);
    #pragma unroll
    for (int i = 0; i < 4; i++)
        #pragma unroll
        for (int j = 0; j < 4; j++)
            atomicAdd(&outp[(th + 16 * i) * NOUT + (tm + 16 * j)], gamma * a2[i][j]);
}

extern "C" void kernel_launch(void* const* d_in, const int* in_sizes, int n_in,
                              void* d_out, int out_size, void* d_ws, size_t ws_size,
                              hipStream_t stream) {
    const float* X  = (const float*)d_in[0];
    const float* Wl = (const float*)d_in[1];
    const float* bl = (const float*)d_in[2];
    float* out = (float*)d_out;
    float* ws  = (float*)d_ws;

    hipMemsetAsync(ws, 0, 1024, stream);
    hipMemsetAsync(out, 0, (size_t)out_size * sizeof(float), stream);

    k_locnet<<<dim3(CHUNKS, BGROUPS), 256, 0, stream>>>(X, Wl, ws);
    k_filters<<<dim3(NOUT, B_, 2), 256, 0, stream>>>(bl, ws);
    k_glimpse<<<dim3(8, B_ * C_), 256, 0, stream>>>(X, bl, ws, out);
}

// Round 3
// 213.676 us; speedup vs baseline: 1.3771x; 1.1507x over previous
//
#include <hip/hip_runtime.h>
#include <math.h>

#define B_ 32
#define C_ 3
#define H_ 512
#define W_ 512
#define NOUT 64
#define FAN (C_*H_*W_)          // 786432

// locnet decomposition
#define CHUNKS 384
#define CELEMS (FAN / CHUNKS)   // 2048
#define BGROUPS 4               // 8 batches per block

// workspace layout (float offsets)
#define P_OFF 0                 // 32*5 accumulators (zeroed each call)
#define FX_OFF 256
#define FY_OFF (FX_OFF + B_*NOUT*W_)

typedef __bf16 bf16x8 __attribute__((ext_vector_type(8)));
typedef float f32x4 __attribute__((ext_vector_type(4)));

// round-to-nearest-even fp32 -> bf16 (as ushort)
__device__ __forceinline__ unsigned short f2bf(float f) {
    unsigned int u = __float_as_uint(f);
    u = (u + 0x7FFFu + ((u >> 16) & 1u)) >> 16;
    return (unsigned short)u;
}
__device__ __forceinline__ float bf2f(unsigned short h) {
    return __uint_as_float(((unsigned int)h) << 16);
}

// ---------------- kernel 1: p[b,j] = sum_i X[b,i] * W_loc[i,j] ----------------
__global__ __launch_bounds__(256) void k_locnet(const float* __restrict__ X,
                                                const float* __restrict__ Wl,
                                                float* __restrict__ ws) {
    const int chunk = blockIdx.x;      // 0..CHUNKS-1
    const int b0 = blockIdx.y * 8;     // 0,8,16,24
    const int t = threadIdx.x;

    float acc[8][5] = {};
    const size_t base = (size_t)chunk * CELEMS;

    for (int k = t; k < CELEMS / 4; k += 256) {   // 2 iterations
        const size_t i0 = base + (size_t)k * 4;
        const float4* W4 = (const float4*)(Wl + i0 * 5);
        float4 w0 = W4[0], w1 = W4[1], w2 = W4[2], w3 = W4[3], w4 = W4[4];
        float wv[20] = {w0.x, w0.y, w0.z, w0.w,
                        w1.x, w1.y, w1.z, w1.w,
                        w2.x, w2.y, w2.z, w2.w,
                        w3.x, w3.y, w3.z, w3.w,
                        w4.x, w4.y, w4.z, w4.w};
        #pragma unroll
        for (int bb = 0; bb < 8; bb++) {
            float4 x = *(const float4*)(X + (size_t)(b0 + bb) * FAN + i0);
            float xv[4] = {x.x, x.y, x.z, x.w};
            #pragma unroll
            for (int e = 0; e < 4; e++)
                #pragma unroll
                for (int j = 0; j < 5; j++)
                    acc[bb][j] += xv[e] * wv[e * 5 + j];
        }
    }

    #pragma unroll
    for (int off = 32; off > 0; off >>= 1)
        #pragma unroll
        for (int bb = 0; bb < 8; bb++)
            #pragma unroll
            for (int j = 0; j < 5; j++)
                acc[bb][j] += __shfl_down(acc[bb][j], off);

    __shared__ float sred[4][40];
    const int wave = t >> 6, lane = t & 63;
    if (lane == 0) {
        #pragma unroll
        for (int bb = 0; bb < 8; bb++)
            #pragma unroll
            for (int j = 0; j < 5; j++)
                sred[wave][bb * 5 + j] = acc[bb][j];
    }
    __syncthreads();
    if (t < 40) {
        float s = sred[0][t] + sred[1][t] + sred[2][t] + sred[3][t];
        atomicAdd(&ws[P_OFF + b0 * 5 + t], s);
    }
}

// ---------------- kernel 2: build normalized Fx [b][n][W], Fy [b][n][H] ----------------
__global__ __launch_bounds__(256) void k_filters(const float* __restrict__ bl,
                                                 float* __restrict__ ws) {
    const int n = blockIdx.x;
    const int b = blockIdx.y;
    const int which = blockIdx.z;
    const int t = threadIdx.x;

    const float p0 = ws[P_OFF + b * 5 + 0] + bl[0];
    const float p1 = ws[P_OFF + b * 5 + 1] + bl[1];
    const float p2 = ws[P_OFF + b * 5 + 2] + bl[2];
    const float p3 = ws[P_OFF + b * 5 + 3] + bl[3];

    const float g = (which == 0) ? 32.f * (p0 + 1.f) : 32.f * (p1 + 1.f);
    const float sigma2 = expf(p2);
    const float inv2s = 0.5f / sigma2;
    const float delta = expf(p3) * (511.0f / 63.0f);
    const float mean = g + delta * ((float)n - 32.5f);

    float d0 = (float)t - mean;
    float f0 = expf(-d0 * d0 * inv2s);
    float d1 = (float)(t + 256) - mean;
    float f1 = expf(-d1 * d1 * inv2s);

    float s = f0 + f1;
    #pragma unroll
    for (int off = 32; off > 0; off >>= 1) s += __shfl_down(s, off);
    __shared__ float sred[4];
    __shared__ float stot;
    const int wave = t >> 6, lane = t & 63;
    if (lane == 0) sred[wave] = s;
    __syncthreads();
    if (t == 0) stot = sred[0] + sred[1] + sred[2] + sred[3] + 1e-4f;
    __syncthreads();
    const float scale = 1.0f / stot;

    float* dst = ws + (which == 0 ? FX_OFF : FY_OFF) + ((size_t)b * NOUT + n) * W_;
    dst[t] = f0 * scale;
    dst[t + 256] = f1 * scale;
}

// ---------------- kernel 3: MFMA glimpse ----------------
// out[b,c] += gamma * Fy_chunk @ (X_chunk @ Fx^T), split-bf16 (hi+lo) MFMA.
// grid (8 hc, 96 bc), 256 threads = 4 waves.
// GEMM1: G[64h x 64m] = X[64h x 512w] @ Fx^T, staged in KC=64 w-chunks.
// GEMM2: P[64n x 64m] = Fy_chunk[64n x 64h] @ G.
// MFMA 16x16x32 bf16. Split product (xh+xl)(fh+fl) ~ xh*fh + xl*fh + xh*fl.
#define KC 64
#define PITCH 72            // ushorts per LDS row (16B-aligned rows, low-conflict)
#define TSZ (64 * PITCH)    // 4608 ushorts per array

__global__ __launch_bounds__(256) void k_glimpse(const float* __restrict__ X,
                                                 const float* __restrict__ bl,
                                                 const float* __restrict__ ws,
                                                 float* __restrict__ out) {
    const int hc = blockIdx.x;   // 0..7
    const int bc = blockIdx.y;   // 0..95
    const int b = bc / 3;
    const int t = threadIdx.x;
    const int lane = t & 63;
    const int wv = t >> 6;       // 0..3
    const int l15 = lane & 15;
    const int quad = lane >> 4;  // 0..3
    const int hbase = hc * 64;

    __shared__ __align__(16) unsigned short lds[4 * TSZ];   // 36864 B
    unsigned short* Xh = lds;             // X hi   -> later Gt hi
    unsigned short* Xl = lds + TSZ;       // X lo   -> later Gt lo
    unsigned short* Fh = lds + 2 * TSZ;   // Fx hi  -> later Fy hi
    unsigned short* Fl = lds + 3 * TSZ;   // Fx lo  -> later Fy lo

    const float* Xp  = X + (size_t)bc * (H_ * W_) + (size_t)hbase * W_;
    const float* Fxp = ws + FX_OFF + (size_t)b * NOUT * W_;
    const float* Fyp = ws + FY_OFF + (size_t)b * NOUT * W_;

    f32x4 acc[4] = {};   // G: wave rows [16wv,+16), 4 m-tiles

    for (int wt = 0; wt < 8; wt++) {
        const int wbase = wt * KC;
        #pragma unroll
        for (int k4 = 0; k4 < 4; k4++) {
            int idx = t + 256 * k4;
            int row = idx >> 4;            // 0..63
            int c4 = (idx & 15) * 4;       // 0,4,..60
            float4 xv = *(const float4*)(Xp + (size_t)row * W_ + wbase + c4);
            float4 fv = *(const float4*)(Fxp + (size_t)row * W_ + wbase + c4);
            float xa[4] = {xv.x, xv.y, xv.z, xv.w};
            float fa[4] = {fv.x, fv.y, fv.z, fv.w};
            unsigned int xhp[2], xlp[2], fhp[2], flp[2];
            #pragma unroll
            for (int hwd = 0; hwd < 2; hwd++) {
                unsigned short h0 = f2bf(xa[2*hwd]);
                unsigned short h1 = f2bf(xa[2*hwd+1]);
                xhp[hwd] = (unsigned int)h0 | ((unsigned int)h1 << 16);
                unsigned short l0 = f2bf(xa[2*hwd] - bf2f(h0));
                unsigned short l1 = f2bf(xa[2*hwd+1] - bf2f(h1));
                xlp[hwd] = (unsigned int)l0 | ((unsigned int)l1 << 16);
                unsigned short g0 = f2bf(fa[2*hwd]);
                unsigned short g1 = f2bf(fa[2*hwd+1]);
                fhp[hwd] = (unsigned int)g0 | ((unsigned int)g1 << 16);
                unsigned short m0 = f2bf(fa[2*hwd] - bf2f(g0));
                unsigned short m1 = f2bf(fa[2*hwd+1] - bf2f(g1));
                flp[hwd] = (unsigned int)m0 | ((unsigned int)m1 << 16);
            }
            int o = row * PITCH + c4;
            *(uint2*)&Xh[o] = make_uint2(xhp[0], xhp[1]);
            *(uint2*)&Xl[o] = make_uint2(xlp[0], xlp[1]);
            *(uint2*)&Fh[o] = make_uint2(fhp[0], fhp[1]);
            *(uint2*)&Fl[o] = make_uint2(flp[0], flp[1]);
        }
        __syncthreads();
        #pragma unroll
        for (int ks = 0; ks < 2; ks++) {
            const int ko = ks * 32 + quad * 8;
            bf16x8 ah = *(const bf16x8*)&Xh[(16 * wv + l15) * PITCH + ko];
            bf16x8 al = *(const bf16x8*)&Xl[(16 * wv + l15) * PITCH + ko];
            #pragma unroll
            for (int mt = 0; mt < 4; mt++) {
                bf16x8 bh = *(const bf16x8*)&Fh[(16 * mt + l15) * PITCH + ko];
                bf16x8 bl2 = *(const bf16x8*)&Fl[(16 * mt + l15) * PITCH + ko];
                acc[mt] = __builtin_amdgcn_mfma_f32_16x16x32_bf16(ah, bh, acc[mt], 0, 0, 0);
                acc[mt] = __builtin_amdgcn_mfma_f32_16x16x32_bf16(al, bh, acc[mt], 0, 0, 0);
                acc[mt] = __builtin_amdgcn_mfma_f32_16x16x32_bf16(ah, bl2, acc[mt], 0, 0, 0);
            }
        }
        __syncthreads();
    }

    // write G transposed as hi/lo into Xh/Xl region: Gt[m][h]
    #pragma unroll
    for (int mt = 0; mt < 4; mt++) {
        unsigned int ghp[2], glp[2];
        unsigned short gh[4], gl[4];
        #pragma unroll
        for (int r = 0; r < 4; r++) {
            float g = acc[mt][r];
            gh[r] = f2bf(g);
            gl[r] = f2bf(g - bf2f(gh[r]));
        }
        ghp[0] = (unsigned int)gh[0] | ((unsigned int)gh[1] << 16);
        ghp[1] = (unsigned int)gh[2] | ((unsigned int)gh[3] << 16);
        glp[0] = (unsigned int)gl[0] | ((unsigned int)gl[1] << 16);
        glp[1] = (unsigned int)gl[2] | ((unsigned int)gl[3] << 16);
        int m = 16 * mt + l15;
        int h = 16 * wv + quad * 4;      // rows quad*4+r, r contiguous
        int o = m * PITCH + h;
        *(uint2*)&Xh[o] = make_uint2(ghp[0], ghp[1]);
        *(uint2*)&Xl[o] = make_uint2(glp[0], glp[1]);
    }

    // stage Fy chunk hi/lo into Fh/Fl: Fys[n][h_local]
    #pragma unroll
    for (int k4 = 0; k4 < 4; k4++) {
        int idx = t + 256 * k4;
        int n = idx >> 4;
        int c4 = (idx & 15) * 4;
        float4 fv = *(const float4*)(Fyp + (size_t)n * W_ + hbase + c4);
        float fa[4] = {fv.x, fv.y, fv.z, fv.w};
        unsigned int fhp[2], flp[2];
        #pragma unroll
        for (int hwd = 0; hwd < 2; hwd++) {
            unsigned short g0 = f2bf(fa[2*hwd]);
            unsigned short g1 = f2bf(fa[2*hwd+1]);
            fhp[hwd] = (unsigned int)g0 | ((unsigned int)g1 << 16);
            unsigned short m0 = f2bf(fa[2*hwd] - bf2f(g0));
            unsigned short m1 = f2bf(fa[2*hwd+1] - bf2f(g1));
            flp[hwd] = (unsigned int)m0 | ((unsigned int)m1 << 16);
        }
        int o = n * PITCH + c4;
        *(uint2*)&Fh[o] = make_uint2(fhp[0], fhp[1]);
        *(uint2*)&Fl[o] = make_uint2(flp[0], flp[1]);
    }
    __syncthreads();

    // GEMM2: P[n][m] = sum_h Fy[n][h] * G[h][m]
    f32x4 p[4] = {};
    #pragma unroll
    for (int ks = 0; ks < 2; ks++) {
        const int ko = ks * 32 + quad * 8;
        bf16x8 yh = *(const bf16x8*)&Fh[(16 * wv + l15) * PITCH + ko];
        bf16x8 yl = *(const bf16x8*)&Fl[(16 * wv + l15) * PITCH + ko];
        #pragma unroll
        for (int mt = 0; mt < 4; mt++) {
            bf16x8 gh = *(const bf16x8*)&Xh[(16 * mt + l15) * PITCH + ko];
            bf16x8 gl = *(const bf16x8*)&Xl[(16 * mt + l15) * PITCH + ko];
            p[mt] = __builtin_amdgcn_mfma_f32_16x16x32_bf16(yh, gh, p[mt], 0, 0, 0);
            p[mt] = __builtin_amdgcn_mfma_f32_16x16x32_bf16(yl, gh, p[mt], 0, 0, 0);
            p[mt] = __builtin_amdgcn_mfma_f32_16x16x32_bf16(yh, gl, p[mt], 0, 0, 0);
        }
    }

    const float gamma = expf(ws[P_OFF + b * 5 + 4] + bl[4]);
    float* outp = out + (size_t)bc * (NOUT * NOUT);
    #pragma unroll
    for (int mt = 0; mt < 4; mt++)
        #pragma unroll
        for (int r = 0; r < 4; r++) {
            int n = 16 * wv + quad * 4 + r;
            int m = 16 * mt + l15;
            atomicAdd(&outp[n * NOUT + m], gamma * p[mt][r]);
        }
}

extern "C" void kernel_launch(void* const* d_in, const int* in_sizes, int n_in,
                              void* d_out, int out_size, void* d_ws, size_t ws_size,
                              hipStream_t stream) {
    const float* X  = (const float*)d_in[0];
    const float* Wl = (const float*)d_in[1];
    const float* bl = (const float*)d_in[2];
    float* out = (float*)d_out;
    float* ws  = (float*)d_ws;

    hipMemsetAsync(ws, 0, 1024, stream);
    hipMemsetAsync(out, 0, (size_t)out_size * sizeof(float), stream);

    k_locnet<<<dim3(CHUNKS, BGROUPS), 256, 0, stream>>>(X, Wl, ws);
    k_filters<<<dim3(NOUT, B_, 2), 256, 0, stream>>>(bl, ws);
    k_glimpse<<<dim3(8, B_ * C_), 256, 0, stream>>>(X, bl, ws, out);
}